// Round 20
// baseline (141.709 us; speedup 1.0000x reference)
//
#include <hip/hip_runtime.h>

#define DD 64
#define BSHIFT 7                 // 128 nodes per bucket
#define NBUCK_MAX 800
#define SEGCAP 4096
#define CBLK 512                 // count blocks (chunks)
#define SBLK 256                 // scatter blocks (= CBLK/2, pairs of chunks)

typedef unsigned short ushort_t;
typedef __attribute__((ext_vector_type(8))) short bf16x8;
typedef __attribute__((ext_vector_type(4))) short bf16x4;
typedef __attribute__((ext_vector_type(4))) float f32x4;

static __device__ __forceinline__ unsigned short f2bf(float f)
{
    unsigned u = __float_as_uint(f);
    unsigned r = (u + 0x7FFFu + ((u >> 16) & 1u)) >> 16;   // round-nearest-even
    return (unsigned short)r;
}
static __device__ __forceinline__ float bf_lo(unsigned w) { return __uint_as_float(w << 16); }
static __device__ __forceinline__ float bf_hi(unsigned w) { return __uint_as_float(w & 0xFFFF0000u); }

// ================= bucketed CSR build (no global atomics) =================

// A: per-block LDS bucket histogram -> partialCnt[bucket*CBLK+blk]
__global__ __launch_bounds__(256)
void bucket_count(const int* __restrict__ dst, int* __restrict__ partialCnt,
                  int nE, int chunk, int nbuck)
{
    __shared__ int bins[NBUCK_MAX];
    int blk = blockIdx.x, t = threadIdx.x;
    for (int i = t; i < nbuck; i += 256) bins[i] = 0;
    __syncthreads();
    int e0 = blk * chunk;
    int e1 = e0 + chunk; if (e1 > nE) e1 = nE;
    for (int e = e0 + t; e < e1; e += 256)
        atomicAdd(&bins[dst[e] >> BSHIFT], 1);
    __syncthreads();
    for (int i = t; i < nbuck; i += 256)
        partialCnt[(size_t)i * CBLK + blk] = bins[i];
}

// A2: per-bucket exclusive scan over its CBLK block counts; total -> bucketTot
__global__ __launch_bounds__(CBLK)
void bucket_scanblocks(int* __restrict__ partialCnt, int* __restrict__ bucketTot)
{
    __shared__ int s[CBLK];
    int b = blockIdx.x, t = threadIdx.x;
    int v = partialCnt[(size_t)b * CBLK + t];
    s[t] = v;
    __syncthreads();
    for (int off = 1; off < CBLK; off <<= 1) {
        int u = (t >= off) ? s[t - off] : 0;
        __syncthreads();
        s[t] += u;
        __syncthreads();
    }
    partialCnt[(size_t)b * CBLK + t] = s[t] - v;   // exclusive
    if (t == CBLK - 1) bucketTot[b] = s[CBLK - 1];
}

// A3: exclusive scan over bucket totals -> bucketBase; also rs[nN]=nE
__global__ __launch_bounds__(1024)
void bucket_scanbase(const int* __restrict__ bucketTot, int* __restrict__ bucketBase,
                     int* __restrict__ rs, int nbuck, int nN)
{
    __shared__ int s[1024];
    int t = threadIdx.x;
    int v = (t < nbuck) ? bucketTot[t] : 0;
    s[t] = v;
    __syncthreads();
    for (int off = 1; off < 1024; off <<= 1) {
        int u = (t >= off) ? s[t - off] : 0;
        __syncthreads();
        s[t] += u;
        __syncthreads();
    }
    if (t < nbuck) bucketBase[t] = s[t] - v;
    if (t == nbuck - 1) {
        bucketBase[nbuck] = s[t];
        rs[nN] = s[t];                // == nE
    }
}

// B: scatter packed (src | dstLocal<<17) into bucket-contiguous buckEdges.
// SBLK blocks, each covering TWO count-chunks (contiguous), so its write
// start within each bucket is the exclusive scan at position 2*blk.
__global__ __launch_bounds__(256)
void bucket_scatter(const int* __restrict__ src, const int* __restrict__ dst,
                    const int* __restrict__ partialCnt,
                    const int* __restrict__ bucketBase,
                    int* __restrict__ buckEdges, int nE, int chunk, int nbuck)
{
    __shared__ int bins[NBUCK_MAX];
    __shared__ int wOff[NBUCK_MAX];
    int blk = blockIdx.x, t = threadIdx.x;
    for (int i = t; i < nbuck; i += 256) {
        bins[i] = 0;
        wOff[i] = bucketBase[i] + partialCnt[(size_t)i * CBLK + 2 * blk];
    }
    __syncthreads();
    int e0 = blk * chunk;
    int e1 = e0 + chunk; if (e1 > nE) e1 = nE;
    for (int e = e0 + t; e < e1; e += 256) {
        int d = dst[e];
        int sv = src[e];
        int bb = d >> BSHIFT;
        int r = atomicAdd(&bins[bb], 1);
        buckEdges[wOff[bb] + r] = sv | ((d & 127) << 17);
    }
}

// C: per-bucket finalize: rs + csr + indf (deg>0 indicator), all-LDS
__global__ __launch_bounds__(256)
void bucket_finalize(const int* __restrict__ buckEdges,
                     const int* __restrict__ bucketBase,
                     int* __restrict__ rs, int* __restrict__ csr,
                     float* __restrict__ indf, int nN)
{
    __shared__ int eLds[SEGCAP];
    __shared__ int segLds[SEGCAP];
    __shared__ int deg[128];
    __shared__ int basec[128];
    __shared__ int cur[128];
    int b = blockIdx.x, t = threadIdx.x;
    int e0 = bucketBase[b], e1 = bucketBase[b + 1];
    int nb = e1 - e0;
    bool staged = (nb <= SEGCAP);
    if (t < 128) deg[t] = 0;
    __syncthreads();
    for (int i = t; i < nb; i += 256) {
        int p = buckEdges[e0 + i];
        if (staged) eLds[i] = p;
        atomicAdd(&deg[(p >> 17) & 127], 1);
    }
    __syncthreads();
    if (t < 128) basec[t] = deg[t];
    __syncthreads();
    for (int off = 1; off < 128; off <<= 1) {
        int u = 0;
        if (t < 128 && t >= off) u = basec[t - off];
        __syncthreads();
        if (t < 128) basec[t] += u;
        __syncthreads();
    }
    int nodeBase = b << BSHIFT;
    if (t < 128) {
        int node = nodeBase + t;
        int ex = basec[t] - deg[t];
        if (node < nN) {
            rs[node] = e0 + ex;
            indf[node] = deg[t] > 0 ? 1.0f : 0.0f;
        }
        cur[t] = ex;
    }
    __syncthreads();
    for (int i = t; i < nb; i += 256) {
        int p = staged ? eLds[i] : buckEdges[e0 + i];
        int dl = (p >> 17) & 127;
        int slot = atomicAdd(&cur[dl], 1);
        int sv = p & 0x1FFFF;
        if (staged) segLds[slot] = sv;
        else        csr[e0 + slot] = sv;
    }
    __syncthreads();
    if (staged)
        for (int i = t; i < nb; i += 256)
            csr[e0 + i] = segLds[i];
}

// ---------- fp32 -> bf16 conversion (8 elems/thread) ----------
__global__ __launch_bounds__(256)
void tobf16_kernel(const float* __restrict__ in, ushort_t* __restrict__ outh,
                   int nTot8)
{
    int i = blockIdx.x * 256 + threadIdx.x;
    if (i >= nTot8) return;
    float4 v0 = *(const float4*)(in + (size_t)i * 8);
    float4 v1 = *(const float4*)(in + (size_t)i * 8 + 4);
    uint4 o;
    o.x = (unsigned)f2bf(v0.x) | ((unsigned)f2bf(v0.y) << 16);
    o.y = (unsigned)f2bf(v0.z) | ((unsigned)f2bf(v0.w) << 16);
    o.z = (unsigned)f2bf(v1.x) | ((unsigned)f2bf(v1.y) << 16);
    o.w = (unsigned)f2bf(v1.z) | ((unsigned)f2bf(v1.w) << 16);
    *(uint4*)(outh + (size_t)i * 8) = o;
}

// ---------- weight precompute: collapse the two layers ----------
__global__ void prep_kernel(const float* __restrict__ W1l,
                            const float* __restrict__ W1r,
                            const float* __restrict__ W2l,
                            const float* __restrict__ W2r,
                            const float* __restrict__ b1,
                            const float* __restrict__ b2,
                            float* __restrict__ MT1, float* __restrict__ MT2,
                            float* __restrict__ MT3, float* __restrict__ c0,
                            float* __restrict__ c1)
{
    int f = blockIdx.x;      // 64 blocks
    int k = threadIdx.x;     // 64 threads
    float m1 = 0.f, m2 = 0.f, m3 = 0.f;
    for (int j = 0; j < DD; ++j) {
        float a2l = W2l[f * DD + j];
        float a2r = W2r[f * DD + j];
        float w1l = W1l[j * DD + k];
        float w1r = W1r[j * DD + k];
        m1 = fmaf(a2l, w1l, m1);
        m2 = fmaf(a2l, w1r, m2);
        m2 = fmaf(a2r, w1l, m2);
        m3 = fmaf(a2r, w1r, m3);
    }
    MT1[k * DD + f] = m1;
    MT2[k * DD + f] = m2;
    MT3[k * DD + f] = m3;
    float t1 = W2l[f * DD + k] * b1[k];
    float t0 = W2r[f * DD + k] * b1[k];
    for (int off = 1; off < 64; off <<= 1) {
        t1 += __shfl_xor(t1, off);
        t0 += __shfl_xor(t0, off);
    }
    if (k == 0) {
        c1[f] = t1;
        c0[f] = t0 + b2[f];
    }
}

// ---------- pack weights into MFMA B-fragment order (bf16) ----------
// k = (l>>4)*4 + (e&3) + 16*(e>>2), col = l&15 (verified by R19 passing).
__global__ __launch_bounds__(256)
void pack_weights(const float* __restrict__ MT1, const float* __restrict__ MT2,
                  const float* __restrict__ MT3, ushort_t* __restrict__ Wp)
{
    int idx = blockIdx.x * 256 + threadIdx.x;     // 0..12287
    if (idx >= 12288) return;
    int e    = idx & 7;
    int lane = (idx >> 3) & 63;
    int ft   = (idx >> 9) & 3;
    int kt   = (idx >> 11) & 1;
    int m    = idx >> 12;
    int kin  = ((lane >> 4) * 4) + (e & 3) + 16 * (e >> 2);
    int gk   = kt * 32 + kin;
    int f    = ft * 16 + (lane & 15);
    const float* MT = (m == 0) ? MT1 : (m == 1) ? MT2 : MT3;
    Wp[idx] = f2bf(MT[gk * DD + f]);
}

// ---------- aggregation, group-per-node: mean over neighbors ----------
__global__ __launch_bounds__(256, 4)
void aggregate_bf16g(const ushort_t* __restrict__ xh,
                     const int* __restrict__ csr,
                     const int* __restrict__ rs,
                     ushort_t* __restrict__ aggrh, int nN)
{
    int lane = threadIdx.x & 63;
    int w = threadIdx.x >> 6;
    int g  = lane >> 3;        // group 0..7: node owner
    int gl = lane & 7;         // lane within group
    int node = (blockIdx.x * 4 + w) * 8 + g;
    int valid = node < nN;
    int nd = valid ? node : nN - 1;
    int beg = rs[nd], end = rs[nd + 1];
    int deg = end - beg;

    float4 aL0 = {0,0,0,0}, aH0 = {0,0,0,0};
    float4 aL1 = {0,0,0,0}, aH1 = {0,0,0,0};
    float4 aL2 = {0,0,0,0}, aH2 = {0,0,0,0};
    float4 aL3 = {0,0,0,0}, aH3 = {0,0,0,0};

#define ROWA(S, L, H)                                                         \
    {                                                                         \
        uint4 v = *(const uint4*)(xh + (size_t)(S) * DD + gl * 8);            \
        L.x += bf_lo(v.x); L.y += bf_hi(v.x);                                 \
        L.z += bf_lo(v.y); L.w += bf_hi(v.y);                                 \
        H.x += bf_lo(v.z); H.y += bf_hi(v.z);                                 \
        H.z += bf_lo(v.w); H.w += bf_hi(v.w);                                 \
    }
#define ROWM(S, MM, L, H)                                                     \
    {                                                                         \
        uint4 v = *(const uint4*)(xh + (size_t)(S) * DD + gl * 8);            \
        L.x = fmaf(MM, bf_lo(v.x), L.x); L.y = fmaf(MM, bf_hi(v.x), L.y);     \
        L.z = fmaf(MM, bf_lo(v.y), L.z); L.w = fmaf(MM, bf_hi(v.y), L.w);     \
        H.x = fmaf(MM, bf_lo(v.z), H.x); H.y = fmaf(MM, bf_hi(v.z), H.y);     \
        H.z = fmaf(MM, bf_lo(v.w), H.z); H.w = fmaf(MM, bf_hi(v.w), H.w);     \
    }

    for (int ch = 0; ch < deg; ch += 8) {
        int ii = ch + gl;
        int myIdx = csr[(ii < deg) ? (beg + ii) : beg];
        int lb = g << 3;
        if (ch + 8 <= deg) {           // full chunk: no masks
            int s0 = __shfl(myIdx, lb + 0);
            int s1 = __shfl(myIdx, lb + 1);
            int s2 = __shfl(myIdx, lb + 2);
            int s3 = __shfl(myIdx, lb + 3);
            ROWA(s0, aL0, aH0) ROWA(s1, aL1, aH1)
            ROWA(s2, aL2, aH2) ROWA(s3, aL3, aH3)
            int s4 = __shfl(myIdx, lb + 4);
            int s5 = __shfl(myIdx, lb + 5);
            int s6 = __shfl(myIdx, lb + 6);
            int s7 = __shfl(myIdx, lb + 7);
            ROWA(s4, aL0, aH0) ROWA(s5, aL1, aH1)
            ROWA(s6, aL2, aH2) ROWA(s7, aL3, aH3)
        } else {                       // tail chunk: masked
            int rem = deg - ch;
            int s0 = __shfl(myIdx, lb + 0);
            int s1 = __shfl(myIdx, lb + 1);
            int s2 = __shfl(myIdx, lb + 2);
            int s3 = __shfl(myIdx, lb + 3);
            float m0 = (0 < rem) ? 1.f : 0.f;
            float m1 = (1 < rem) ? 1.f : 0.f;
            float m2 = (2 < rem) ? 1.f : 0.f;
            float m3 = (3 < rem) ? 1.f : 0.f;
            ROWM(s0, m0, aL0, aH0) ROWM(s1, m1, aL1, aH1)
            ROWM(s2, m2, aL2, aH2) ROWM(s3, m3, aL3, aH3)
            int s4 = __shfl(myIdx, lb + 4);
            int s5 = __shfl(myIdx, lb + 5);
            int s6 = __shfl(myIdx, lb + 6);
            int s7 = __shfl(myIdx, lb + 7);
            float m4 = (4 < rem) ? 1.f : 0.f;
            float m5 = (5 < rem) ? 1.f : 0.f;
            float m6 = (6 < rem) ? 1.f : 0.f;
            float m7 = (7 < rem) ? 1.f : 0.f;
            ROWM(s4, m4, aL0, aH0) ROWM(s5, m5, aL1, aH1)
            ROWM(s6, m6, aL2, aH2) ROWM(s7, m7, aL3, aH3)
        }
    }
#undef ROWA
#undef ROWM

    float4 L, H;
    L.x = (aL0.x + aL1.x) + (aL2.x + aL3.x);
    L.y = (aL0.y + aL1.y) + (aL2.y + aL3.y);
    L.z = (aL0.z + aL1.z) + (aL2.z + aL3.z);
    L.w = (aL0.w + aL1.w) + (aL2.w + aL3.w);
    H.x = (aH0.x + aH1.x) + (aH2.x + aH3.x);
    H.y = (aH0.y + aH1.y) + (aH2.y + aH3.y);
    H.z = (aH0.z + aH1.z) + (aH2.z + aH3.z);
    H.w = (aH0.w + aH1.w) + (aH2.w + aH3.w);
    if (valid) {
        float inv = 1.0f / (float)(deg > 0 ? deg : 1);
        uint4 o;
        o.x = (unsigned)f2bf(L.x * inv) | ((unsigned)f2bf(L.y * inv) << 16);
        o.y = (unsigned)f2bf(L.z * inv) | ((unsigned)f2bf(L.w * inv) << 16);
        o.z = (unsigned)f2bf(H.x * inv) | ((unsigned)f2bf(H.y * inv) << 16);
        o.w = (unsigned)f2bf(H.z * inv) | ((unsigned)f2bf(H.w * inv) << 16);
        *(uint4*)(aggrh + (size_t)node * DD + gl * 8) = o;
    }
}

// ---------- MFMA tri-dense: out = agg2@M1.T + agg1@M2.T + x@M3.T + bias ----
// One wave = 16 nodes x 64 f. No LDS/barriers. ALL 12 A-loads + epilogue
// scalars hoisted to entry (12 independent loads in flight before the MFMA
// chain); B-frags stream per (m,kt) from the L1-hot packed table.
__global__ __launch_bounds__(256)
void tri_dense_mfma(const ushort_t* __restrict__ agg2h,
                    const ushort_t* __restrict__ agg1h,
                    const ushort_t* __restrict__ xh,
                    const ushort_t* __restrict__ Wp,
                    const float* __restrict__ c0,
                    const float* __restrict__ c1,
                    const float* __restrict__ indf,
                    float* __restrict__ out, int nN)
{
    int lane = threadIdx.x & 63;
    int w = threadIdx.x >> 6;
    int base = (blockIdx.x * 4 + w) * 16;
    if (base >= nN) return;
    int mrow = lane & 15;          // A row within tile / D col (=f low bits)
    int kg   = lane >> 4;          // k-group / D row-group
    size_t rowoff = (size_t)(base + mrow) * DD + kg * 4;

    // hoist all A loads (3 srcs x 2 kt x {lo,hi} = 12 independent 8B loads)
    bf16x4 aLo[3][2], aHi[3][2];
#pragma unroll
    for (int m = 0; m < 3; ++m) {
        const ushort_t* sp = (m == 0) ? agg2h : (m == 1) ? agg1h : xh;
#pragma unroll
        for (int kt = 0; kt < 2; ++kt) {
            aLo[m][kt] = *(const bf16x4*)(sp + rowoff + kt * 32);
            aHi[m][kt] = *(const bf16x4*)(sp + rowoff + kt * 32 + 16);
        }
    }
    // epilogue scalars early (independent loads)
    float ind0 = indf[base + kg * 4 + 0];
    float ind1 = indf[base + kg * 4 + 1];
    float ind2 = indf[base + kg * 4 + 2];
    float ind3 = indf[base + kg * 4 + 3];
    float c0v[4], c1v[4];
#pragma unroll
    for (int ft = 0; ft < 4; ++ft) {
        c0v[ft] = c0[ft * 16 + mrow];
        c1v[ft] = c1[ft * 16 + mrow];
    }

    f32x4 acc0 = {0,0,0,0}, acc1 = {0,0,0,0}, acc2 = {0,0,0,0}, acc3 = {0,0,0,0};
#pragma unroll
    for (int m = 0; m < 3; ++m) {
#pragma unroll
        for (int kt = 0; kt < 2; ++kt) {
            bf16x8 a;
            a[0] = aLo[m][kt][0]; a[1] = aLo[m][kt][1];
            a[2] = aLo[m][kt][2]; a[3] = aLo[m][kt][3];
            a[4] = aHi[m][kt][0]; a[5] = aHi[m][kt][1];
            a[6] = aHi[m][kt][2]; a[7] = aHi[m][kt][3];
            const ushort_t* wp = Wp + ((m * 2 + kt) * 4) * 512 + lane * 8;
            bf16x8 b0 = *(const bf16x8*)(wp);
            bf16x8 b1 = *(const bf16x8*)(wp + 512);
            bf16x8 b2 = *(const bf16x8*)(wp + 1024);
            bf16x8 b3 = *(const bf16x8*)(wp + 1536);
            acc0 = __builtin_amdgcn_mfma_f32_16x16x32_bf16(a, b0, acc0, 0, 0, 0);
            acc1 = __builtin_amdgcn_mfma_f32_16x16x32_bf16(a, b1, acc1, 0, 0, 0);
            acc2 = __builtin_amdgcn_mfma_f32_16x16x32_bf16(a, b2, acc2, 0, 0, 0);
            acc3 = __builtin_amdgcn_mfma_f32_16x16x32_bf16(a, b3, acc3, 0, 0, 0);
        }
    }

#define STORE_T(ACC, ft)                                                      \
    {                                                                         \
        int f = (ft) * 16 + mrow;                                             \
        size_t o = (size_t)(base + kg * 4) * DD + f;                          \
        out[o         ] = ACC[0] + c0v[ft] + ind0 * c1v[ft];                  \
        out[o + DD    ] = ACC[1] + c0v[ft] + ind1 * c1v[ft];                  \
        out[o + 2 * DD] = ACC[2] + c0v[ft] + ind2 * c1v[ft];                  \
        out[o + 3 * DD] = ACC[3] + c0v[ft] + ind3 * c1v[ft];                  \
    }
    STORE_T(acc0, 0) STORE_T(acc1, 1) STORE_T(acc2, 2) STORE_T(acc3, 3)
#undef STORE_T
}

extern "C" void kernel_launch(void* const* d_in, const int* in_sizes, int n_in,
                              void* d_out, int out_size, void* d_ws, size_t ws_size,
                              hipStream_t stream)
{
    const float* x   = (const float*)d_in[0];
    const int*   ei  = (const int*)d_in[1];
    const float* W1l = (const float*)d_in[2];
    const float* b1l = (const float*)d_in[3];
    const float* W1r = (const float*)d_in[4];
    const float* W2l = (const float*)d_in[5];
    const float* b2l = (const float*)d_in[6];
    const float* W2r = (const float*)d_in[7];
    float* out = (float*)d_out;

    int nN = in_sizes[0] / DD;   // 100000
    int nE = in_sizes[1] / 2;    // 1600000
    const int* src = ei;
    const int* dst = ei + nE;

    int nbuck = (nN + 127) >> BSHIFT;          // 782
    int cchunk = (nE + CBLK - 1) / CBLK;       // 3125
    int schunk = cchunk * 2;                   // 6250 (2 count-chunks/block)

    // ws layout (float-sized slots):
    // rs[nN+1] | partialCnt[nbuck*CBLK] | bucketTot[nbuck] | bucketBase[nbuck+1] |
    // csr[nE] | buckEdges[nE] | MT1,MT2,MT3[4096 ea] | c0,c1[64 ea] |
    // xh[nN*32] | agg1h[nN*32] | agg2h[nN*32] | indf[nN] | Wp[12288 bf16]
    int* rs         = (int*)d_ws;
    int* partialCnt = rs + nN + 1;
    int* bucketTot  = partialCnt + (size_t)nbuck * CBLK;
    int* bucketBase = bucketTot + nbuck;
    int* csr        = bucketBase + nbuck + 1;
    int* buckEdges  = csr + nE;
    size_t ofs = (size_t)(buckEdges + nE - (int*)d_ws);
    ofs = (ofs + 3) & ~(size_t)3;
    float* MT1 = (float*)d_ws + ofs;
    float* MT2 = MT1 + DD * DD;
    float* MT3 = MT2 + DD * DD;
    float* c0 = MT3 + DD * DD;
    float* c1 = c0 + DD;
    float* xh_f    = c1 + DD;
    float* agg1h_f = xh_f + (size_t)nN * 32;
    float* agg2h_f = agg1h_f + (size_t)nN * 32;
    float* indf    = agg2h_f + (size_t)nN * 32;
    ushort_t* Wp   = (ushort_t*)(indf + nN);
    ushort_t* xh    = (ushort_t*)xh_f;
    ushort_t* agg1h = (ushort_t*)agg1h_f;
    ushort_t* agg2h = (ushort_t*)agg2h_f;

    int ncv  = (nN * 32 / 4 + 255) / 256;      // tobf16 blocks
    int nagg = (nN + 31) / 32;                 // aggregate blocks
    int nmf  = (nN / 16 + 3) / 4;              // mfma dense blocks (4 waves ea)

    // CSR build — bucketed, zero global atomics, all-coalesced streams
    bucket_count<<<CBLK, 256, 0, stream>>>(dst, partialCnt, nE, cchunk, nbuck);
    bucket_scanblocks<<<nbuck, CBLK, 0, stream>>>(partialCnt, bucketTot);
    bucket_scanbase<<<1, 1024, 0, stream>>>(bucketTot, bucketBase, rs, nbuck, nN);
    bucket_scatter<<<SBLK, 256, 0, stream>>>(src, dst, partialCnt, bucketBase,
                                             buckEdges, nE, schunk, nbuck);
    bucket_finalize<<<nbuck, 256, 0, stream>>>(buckEdges, bucketBase, rs, csr,
                                               indf, nN);

    // weight collapse + pack + x -> bf16
    prep_kernel<<<64, 64, 0, stream>>>(W1l, W1r, W2l, W2r, b1l, b2l,
                                       MT1, MT2, MT3, c0, c1);
    pack_weights<<<48, 256, 0, stream>>>(MT1, MT2, MT3, Wp);
    tobf16_kernel<<<ncv, 256, 0, stream>>>(x, xh, nN * DD / 8);

    // two bf16 aggregations (group-per-node)
    aggregate_bf16g<<<nagg, 256, 0, stream>>>(xh, csr, rs, agg1h, nN);
    aggregate_bf16g<<<nagg, 256, 0, stream>>>(agg1h, csr, rs, agg2h, nN);

    // MFMA dense: 16 nodes/wave, hoisted A-loads, no LDS, no barriers
    tri_dense_mfma<<<nmf, 256, 0, stream>>>(agg2h, agg1h, xh, Wp,
                                            c0, c1, indf, out, nN);
}

// Round 21
// 134.236 us; speedup vs baseline: 1.0557x; 1.0557x over previous
//
#include <hip/hip_runtime.h>

#define DD 64
#define BSHIFT 7                 // 128 nodes per bucket
#define NBUCK_MAX 800
#define SEGCAP 4096
#define CBLK 512                 // count blocks (chunks)
#define SBLK 256                 // scatter blocks (= CBLK/2, pairs of chunks)

typedef unsigned short ushort_t;
typedef unsigned char uchar_t;
typedef __attribute__((ext_vector_type(8))) short bf16x8;
typedef __attribute__((ext_vector_type(4))) short bf16x4;
typedef __attribute__((ext_vector_type(4))) float f32x4;
typedef __attribute__((ext_vector_type(2))) float f32x2;

#if defined(__has_builtin)
#if __has_builtin(__builtin_amdgcn_cvt_pk_f32_fp8) && __has_builtin(__builtin_amdgcn_cvt_pk_fp8_f32)
#define HW_FP8 1
#endif
#endif
#ifndef HW_FP8
#define HW_FP8 0
#endif

static __device__ __forceinline__ unsigned short f2bf(float f)
{
    unsigned u = __float_as_uint(f);
    unsigned r = (u + 0x7FFFu + ((u >> 16) & 1u)) >> 16;   // round-nearest-even
    return (unsigned short)r;
}
static __device__ __forceinline__ float bf_lo(unsigned w) { return __uint_as_float(w << 16); }
static __device__ __forceinline__ float bf_hi(unsigned w) { return __uint_as_float(w & 0xFFFF0000u); }

// ---- OCP e4m3fn helpers (HW cvt on gfx950; exact SW fallback via 2^±120) --
static __device__ __forceinline__ unsigned f2q8_sw(float f)
{
    unsigned u = __float_as_uint(f);
    unsigned s = (u >> 31) << 7;
    unsigned um = __float_as_uint(__uint_as_float(u & 0x7FFFFFFFu) * 0x1.0p-120f);
    unsigned q = (um + 0x7FFFFu + ((um >> 20) & 1u)) >> 20;
    if (q > 0x7Eu) q = 0x7Eu;
    return s | q;
}
static __device__ __forceinline__ float q2f_sw(unsigned b)
{
    unsigned u = ((b & 0x80u) << 24) | ((b & 0x7Fu) << 20);
    return __uint_as_float(u) * 0x1.0p120f;
}
// decode 2 fp8 from selected 16-bit half of u
template<int WORD>
static __device__ __forceinline__ f32x2 cvt2(unsigned u)
{
#if HW_FP8
    return __builtin_amdgcn_cvt_pk_f32_fp8(u, WORD);
#else
    unsigned b0 = (u >> (WORD * 16)) & 0xFFu;
    unsigned b1 = (u >> (WORD * 16 + 8)) & 0xFFu;
    f32x2 r; r[0] = q2f_sw(b0); r[1] = q2f_sw(b1);
    return r;
#endif
}
// pack 2 f32 into selected 16-bit half of old
template<int WORD>
static __device__ __forceinline__ unsigned pk8(float x, float y, unsigned old)
{
#if HW_FP8
    return __builtin_amdgcn_cvt_pk_fp8_f32(x, y, old, WORD);
#else
    unsigned q = f2q8_sw(x) | (f2q8_sw(y) << 8);
    return WORD ? ((old & 0x0000FFFFu) | (q << 16)) : ((old & 0xFFFF0000u) | q);
#endif
}

// ================= bucketed CSR build (no global atomics) =================

__global__ __launch_bounds__(256)
void bucket_count(const int* __restrict__ dst, int* __restrict__ partialCnt,
                  int nE, int chunk, int nbuck)
{
    __shared__ int bins[NBUCK_MAX];
    int blk = blockIdx.x, t = threadIdx.x;
    for (int i = t; i < nbuck; i += 256) bins[i] = 0;
    __syncthreads();
    int e0 = blk * chunk;
    int e1 = e0 + chunk; if (e1 > nE) e1 = nE;
    for (int e = e0 + t; e < e1; e += 256)
        atomicAdd(&bins[dst[e] >> BSHIFT], 1);
    __syncthreads();
    for (int i = t; i < nbuck; i += 256)
        partialCnt[(size_t)i * CBLK + blk] = bins[i];
}

__global__ __launch_bounds__(CBLK)
void bucket_scanblocks(int* __restrict__ partialCnt, int* __restrict__ bucketTot)
{
    __shared__ int s[CBLK];
    int b = blockIdx.x, t = threadIdx.x;
    int v = partialCnt[(size_t)b * CBLK + t];
    s[t] = v;
    __syncthreads();
    for (int off = 1; off < CBLK; off <<= 1) {
        int u = (t >= off) ? s[t - off] : 0;
        __syncthreads();
        s[t] += u;
        __syncthreads();
    }
    partialCnt[(size_t)b * CBLK + t] = s[t] - v;   // exclusive
    if (t == CBLK - 1) bucketTot[b] = s[CBLK - 1];
}

__global__ __launch_bounds__(1024)
void bucket_scanbase(const int* __restrict__ bucketTot, int* __restrict__ bucketBase,
                     int* __restrict__ rs, int nbuck, int nN)
{
    __shared__ int s[1024];
    int t = threadIdx.x;
    int v = (t < nbuck) ? bucketTot[t] : 0;
    s[t] = v;
    __syncthreads();
    for (int off = 1; off < 1024; off <<= 1) {
        int u = (t >= off) ? s[t - off] : 0;
        __syncthreads();
        s[t] += u;
        __syncthreads();
    }
    if (t < nbuck) bucketBase[t] = s[t] - v;
    if (t == nbuck - 1) {
        bucketBase[nbuck] = s[t];
        rs[nN] = s[t];                // == nE
    }
}

__global__ __launch_bounds__(256)
void bucket_scatter(const int* __restrict__ src, const int* __restrict__ dst,
                    const int* __restrict__ partialCnt,
                    const int* __restrict__ bucketBase,
                    int* __restrict__ buckEdges, int nE, int chunk, int nbuck)
{
    __shared__ int bins[NBUCK_MAX];
    __shared__ int wOff[NBUCK_MAX];
    int blk = blockIdx.x, t = threadIdx.x;
    for (int i = t; i < nbuck; i += 256) {
        bins[i] = 0;
        wOff[i] = bucketBase[i] + partialCnt[(size_t)i * CBLK + 2 * blk];
    }
    __syncthreads();
    int e0 = blk * chunk;
    int e1 = e0 + chunk; if (e1 > nE) e1 = nE;
    for (int e = e0 + t; e < e1; e += 256) {
        int d = dst[e];
        int sv = src[e];
        int bb = d >> BSHIFT;
        int r = atomicAdd(&bins[bb], 1);
        buckEdges[wOff[bb] + r] = sv | ((d & 127) << 17);
    }
}

__global__ __launch_bounds__(256)
void bucket_finalize(const int* __restrict__ buckEdges,
                     const int* __restrict__ bucketBase,
                     int* __restrict__ rs, int* __restrict__ csr,
                     float* __restrict__ indf, int nN)
{
    __shared__ int eLds[SEGCAP];
    __shared__ int segLds[SEGCAP];
    __shared__ int deg[128];
    __shared__ int basec[128];
    __shared__ int cur[128];
    int b = blockIdx.x, t = threadIdx.x;
    int e0 = bucketBase[b], e1 = bucketBase[b + 1];
    int nb = e1 - e0;
    bool staged = (nb <= SEGCAP);
    if (t < 128) deg[t] = 0;
    __syncthreads();
    for (int i = t; i < nb; i += 256) {
        int p = buckEdges[e0 + i];
        if (staged) eLds[i] = p;
        atomicAdd(&deg[(p >> 17) & 127], 1);
    }
    __syncthreads();
    if (t < 128) basec[t] = deg[t];
    __syncthreads();
    for (int off = 1; off < 128; off <<= 1) {
        int u = 0;
        if (t < 128 && t >= off) u = basec[t - off];
        __syncthreads();
        if (t < 128) basec[t] += u;
        __syncthreads();
    }
    int nodeBase = b << BSHIFT;
    if (t < 128) {
        int node = nodeBase + t;
        int ex = basec[t] - deg[t];
        if (node < nN) {
            rs[node] = e0 + ex;
            indf[node] = deg[t] > 0 ? 1.0f : 0.0f;
        }
        cur[t] = ex;
    }
    __syncthreads();
    for (int i = t; i < nb; i += 256) {
        int p = staged ? eLds[i] : buckEdges[e0 + i];
        int dl = (p >> 17) & 127;
        int slot = atomicAdd(&cur[dl], 1);
        int sv = p & 0x1FFFF;
        if (staged) segLds[slot] = sv;
        else        csr[e0 + slot] = sv;
    }
    __syncthreads();
    if (staged)
        for (int i = t; i < nb; i += 256)
            csr[e0 + i] = segLds[i];
}

// ---------- fp32 -> fp8 conversion of x (8 elems/thread) ----------
__global__ __launch_bounds__(256)
void tofp8_kernel(const float* __restrict__ in, uchar_t* __restrict__ outq,
                  int nTot8)
{
    int i = blockIdx.x * 256 + threadIdx.x;
    if (i >= nTot8) return;
    float4 v0 = *(const float4*)(in + (size_t)i * 8);
    float4 v1 = *(const float4*)(in + (size_t)i * 8 + 4);
    unsigned w0 = pk8<0>(v0.x, v0.y, 0u);
    w0 = pk8<1>(v0.z, v0.w, w0);
    unsigned w1 = pk8<0>(v1.x, v1.y, 0u);
    w1 = pk8<1>(v1.z, v1.w, w1);
    uint2 o; o.x = w0; o.y = w1;
    *(uint2*)(outq + (size_t)i * 8) = o;
}

// ---------- weight precompute: collapse the two layers ----------
__global__ void prep_kernel(const float* __restrict__ W1l,
                            const float* __restrict__ W1r,
                            const float* __restrict__ W2l,
                            const float* __restrict__ W2r,
                            const float* __restrict__ b1,
                            const float* __restrict__ b2,
                            float* __restrict__ MT1, float* __restrict__ MT2,
                            float* __restrict__ MT3, float* __restrict__ c0,
                            float* __restrict__ c1)
{
    int f = blockIdx.x;      // 64 blocks
    int k = threadIdx.x;     // 64 threads
    float m1 = 0.f, m2 = 0.f, m3 = 0.f;
    for (int j = 0; j < DD; ++j) {
        float a2l = W2l[f * DD + j];
        float a2r = W2r[f * DD + j];
        float w1l = W1l[j * DD + k];
        float w1r = W1r[j * DD + k];
        m1 = fmaf(a2l, w1l, m1);
        m2 = fmaf(a2l, w1r, m2);
        m2 = fmaf(a2r, w1l, m2);
        m3 = fmaf(a2r, w1r, m3);
    }
    MT1[k * DD + f] = m1;
    MT2[k * DD + f] = m2;
    MT3[k * DD + f] = m3;
    float t1 = W2l[f * DD + k] * b1[k];
    float t0 = W2r[f * DD + k] * b1[k];
    for (int off = 1; off < 64; off <<= 1) {
        t1 += __shfl_xor(t1, off);
        t0 += __shfl_xor(t0, off);
    }
    if (k == 0) {
        c1[f] = t1;
        c0[f] = t0 + b2[f];
    }
}

// ---------- pack weights into MFMA B-fragment order (bf16) ----------
// k = (l>>4)*4 + (e&3) + 16*(e>>2), col = l&15 (verified by R19 passing).
__global__ __launch_bounds__(256)
void pack_weights(const float* __restrict__ MT1, const float* __restrict__ MT2,
                  const float* __restrict__ MT3, ushort_t* __restrict__ Wp)
{
    int idx = blockIdx.x * 256 + threadIdx.x;     // 0..12287
    if (idx >= 12288) return;
    int e    = idx & 7;
    int lane = (idx >> 3) & 63;
    int ft   = (idx >> 9) & 3;
    int kt   = (idx >> 11) & 1;
    int m    = idx >> 12;
    int kin  = ((lane >> 4) * 4) + (e & 3) + 16 * (e >> 2);
    int gk   = kt * 32 + kin;
    int f    = ft * 16 + (lane & 15);
    const float* MT = (m == 0) ? MT1 : (m == 1) ? MT2 : MT3;
    Wp[idx] = f2bf(MT[gk * DD + f]);
}

// ---------- aggregation over fp8 rows (64B = 1 line/row) ----------
// 8-lane group per node; lane gl owns features [gl*8, gl*8+8). fp32 accum;
// outputs bf16 (for dense A) and optionally fp8 (for the next gather).
__global__ __launch_bounds__(256, 4)
void aggregate_fp8(const uchar_t* __restrict__ xq,
                   const int* __restrict__ csr,
                   const int* __restrict__ rs,
                   ushort_t* __restrict__ aggrh,
                   uchar_t* __restrict__ aggrq,     // may be null
                   int nN)
{
    int lane = threadIdx.x & 63;
    int w = threadIdx.x >> 6;
    int g  = lane >> 3;        // group: node owner
    int gl = lane & 7;         // lane within group
    int node = (blockIdx.x * 4 + w) * 8 + g;
    int valid = node < nN;
    int nd = valid ? node : nN - 1;
    int beg = rs[nd], end = rs[nd + 1];
    int deg = end - beg;

    float4 A0 = {0,0,0,0}, B0 = {0,0,0,0};
    float4 A1 = {0,0,0,0}, B1 = {0,0,0,0};
    float4 A2 = {0,0,0,0}, B2 = {0,0,0,0};
    float4 A3 = {0,0,0,0}, B3 = {0,0,0,0};

#define ROWA(S, A, B)                                                         \
    {                                                                         \
        uint2 v = *(const uint2*)(xq + (size_t)(S) * DD + gl * 8);            \
        f32x2 f;                                                              \
        f = cvt2<0>(v.x); A.x += f[0]; A.y += f[1];                           \
        f = cvt2<1>(v.x); A.z += f[0]; A.w += f[1];                           \
        f = cvt2<0>(v.y); B.x += f[0]; B.y += f[1];                           \
        f = cvt2<1>(v.y); B.z += f[0]; B.w += f[1];                           \
    }
#define ROWM(S, MM, A, B)                                                     \
    {                                                                         \
        uint2 v = *(const uint2*)(xq + (size_t)(S) * DD + gl * 8);            \
        f32x2 f;                                                              \
        f = cvt2<0>(v.x); A.x = fmaf(MM, f[0], A.x); A.y = fmaf(MM, f[1], A.y); \
        f = cvt2<1>(v.x); A.z = fmaf(MM, f[0], A.z); A.w = fmaf(MM, f[1], A.w); \
        f = cvt2<0>(v.y); B.x = fmaf(MM, f[0], B.x); B.y = fmaf(MM, f[1], B.y); \
        f = cvt2<1>(v.y); B.z = fmaf(MM, f[0], B.z); B.w = fmaf(MM, f[1], B.w); \
    }

    for (int ch = 0; ch < deg; ch += 8) {
        int ii = ch + gl;
        int myIdx = csr[(ii < deg) ? (beg + ii) : beg];
        int lb = g << 3;
        if (ch + 8 <= deg) {           // full chunk: no masks
            int s0 = __shfl(myIdx, lb + 0);
            int s1 = __shfl(myIdx, lb + 1);
            int s2 = __shfl(myIdx, lb + 2);
            int s3 = __shfl(myIdx, lb + 3);
            ROWA(s0, A0, B0) ROWA(s1, A1, B1)
            ROWA(s2, A2, B2) ROWA(s3, A3, B3)
            int s4 = __shfl(myIdx, lb + 4);
            int s5 = __shfl(myIdx, lb + 5);
            int s6 = __shfl(myIdx, lb + 6);
            int s7 = __shfl(myIdx, lb + 7);
            ROWA(s4, A0, B0) ROWA(s5, A1, B1)
            ROWA(s6, A2, B2) ROWA(s7, A3, B3)
        } else {                       // tail chunk: masked
            int rem = deg - ch;
            int s0 = __shfl(myIdx, lb + 0);
            int s1 = __shfl(myIdx, lb + 1);
            int s2 = __shfl(myIdx, lb + 2);
            int s3 = __shfl(myIdx, lb + 3);
            float m0 = (0 < rem) ? 1.f : 0.f;
            float m1 = (1 < rem) ? 1.f : 0.f;
            float m2 = (2 < rem) ? 1.f : 0.f;
            float m3 = (3 < rem) ? 1.f : 0.f;
            ROWM(s0, m0, A0, B0) ROWM(s1, m1, A1, B1)
            ROWM(s2, m2, A2, B2) ROWM(s3, m3, A3, B3)
            int s4 = __shfl(myIdx, lb + 4);
            int s5 = __shfl(myIdx, lb + 5);
            int s6 = __shfl(myIdx, lb + 6);
            int s7 = __shfl(myIdx, lb + 7);
            float m4 = (4 < rem) ? 1.f : 0.f;
            float m5 = (5 < rem) ? 1.f : 0.f;
            float m6 = (6 < rem) ? 1.f : 0.f;
            float m7 = (7 < rem) ? 1.f : 0.f;
            ROWM(s4, m4, A0, B0) ROWM(s5, m5, A1, B1)
            ROWM(s6, m6, A2, B2) ROWM(s7, m7, A3, B3)
        }
    }
#undef ROWA
#undef ROWM

    if (valid) {
        float inv = 1.0f / (float)(deg > 0 ? deg : 1);
        float4 L, H;
        L.x = ((A0.x + A1.x) + (A2.x + A3.x)) * inv;
        L.y = ((A0.y + A1.y) + (A2.y + A3.y)) * inv;
        L.z = ((A0.z + A1.z) + (A2.z + A3.z)) * inv;
        L.w = ((A0.w + A1.w) + (A2.w + A3.w)) * inv;
        H.x = ((B0.x + B1.x) + (B2.x + B3.x)) * inv;
        H.y = ((B0.y + B1.y) + (B2.y + B3.y)) * inv;
        H.z = ((B0.z + B1.z) + (B2.z + B3.z)) * inv;
        H.w = ((B0.w + B1.w) + (B2.w + B3.w)) * inv;
        uint4 o;
        o.x = (unsigned)f2bf(L.x) | ((unsigned)f2bf(L.y) << 16);
        o.y = (unsigned)f2bf(L.z) | ((unsigned)f2bf(L.w) << 16);
        o.z = (unsigned)f2bf(H.x) | ((unsigned)f2bf(H.y) << 16);
        o.w = (unsigned)f2bf(H.z) | ((unsigned)f2bf(H.w) << 16);
        *(uint4*)(aggrh + (size_t)node * DD + gl * 8) = o;
        if (aggrq) {
            unsigned w0 = pk8<0>(L.x, L.y, 0u);
            w0 = pk8<1>(L.z, L.w, w0);
            unsigned w1 = pk8<0>(H.x, H.y, 0u);
            w1 = pk8<1>(H.z, H.w, w1);
            uint2 q; q.x = w0; q.y = w1;
            *(uint2*)(aggrq + (size_t)node * DD + gl * 8) = q;
        }
    }
}

// ---------- MFMA tri-dense: out = agg2@M1.T + agg1@M2.T + x@M3.T + bias ----
// One wave = 16 nodes x 64 f. agg2/agg1 in bf16; x read as f32 (full
// precision) and converted in-register. B-frags from L1-hot packed table.
__global__ __launch_bounds__(256)
void tri_dense_mfma(const ushort_t* __restrict__ agg2h,
                    const ushort_t* __restrict__ agg1h,
                    const float* __restrict__ xf,
                    const ushort_t* __restrict__ Wp,
                    const float* __restrict__ c0,
                    const float* __restrict__ c1,
                    const float* __restrict__ indf,
                    float* __restrict__ out, int nN)
{
    int lane = threadIdx.x & 63;
    int w = threadIdx.x >> 6;
    int base = (blockIdx.x * 4 + w) * 16;
    if (base >= nN) return;
    int mrow = lane & 15;          // A row within tile / D col (=f low bits)
    int kg   = lane >> 4;          // k-group / D row-group
    size_t rowoff = (size_t)(base + mrow) * DD + kg * 4;

    // hoist A loads: agg2/agg1 bf16 (8 loads), x f32 (4x float4)
    bf16x4 aLo[2][2], aHi[2][2];
#pragma unroll
    for (int m = 0; m < 2; ++m) {
        const ushort_t* sp = (m == 0) ? agg2h : agg1h;
#pragma unroll
        for (int kt = 0; kt < 2; ++kt) {
            aLo[m][kt] = *(const bf16x4*)(sp + rowoff + kt * 32);
            aHi[m][kt] = *(const bf16x4*)(sp + rowoff + kt * 32 + 16);
        }
    }
    float4 xlo[2], xhi[2];
#pragma unroll
    for (int kt = 0; kt < 2; ++kt) {
        xlo[kt] = *(const float4*)(xf + rowoff + kt * 32);
        xhi[kt] = *(const float4*)(xf + rowoff + kt * 32 + 16);
    }
    float ind0 = indf[base + kg * 4 + 0];
    float ind1 = indf[base + kg * 4 + 1];
    float ind2 = indf[base + kg * 4 + 2];
    float ind3 = indf[base + kg * 4 + 3];
    float c0v[4], c1v[4];
#pragma unroll
    for (int ft = 0; ft < 4; ++ft) {
        c0v[ft] = c0[ft * 16 + mrow];
        c1v[ft] = c1[ft * 16 + mrow];
    }

    f32x4 acc0 = {0,0,0,0}, acc1 = {0,0,0,0}, acc2 = {0,0,0,0}, acc3 = {0,0,0,0};
#pragma unroll
    for (int m = 0; m < 3; ++m) {
#pragma unroll
        for (int kt = 0; kt < 2; ++kt) {
            bf16x8 a;
            if (m < 2) {
                a[0] = aLo[m][kt][0]; a[1] = aLo[m][kt][1];
                a[2] = aLo[m][kt][2]; a[3] = aLo[m][kt][3];
                a[4] = aHi[m][kt][0]; a[5] = aHi[m][kt][1];
                a[6] = aHi[m][kt][2]; a[7] = aHi[m][kt][3];
            } else {
                a[0] = (short)f2bf(xlo[kt].x); a[1] = (short)f2bf(xlo[kt].y);
                a[2] = (short)f2bf(xlo[kt].z); a[3] = (short)f2bf(xlo[kt].w);
                a[4] = (short)f2bf(xhi[kt].x); a[5] = (short)f2bf(xhi[kt].y);
                a[6] = (short)f2bf(xhi[kt].z); a[7] = (short)f2bf(xhi[kt].w);
            }
            const ushort_t* wp = Wp + ((m * 2 + kt) * 4) * 512 + lane * 8;
            bf16x8 b0 = *(const bf16x8*)(wp);
            bf16x8 b1 = *(const bf16x8*)(wp + 512);
            bf16x8 b2 = *(const bf16x8*)(wp + 1024);
            bf16x8 b3 = *(const bf16x8*)(wp + 1536);
            acc0 = __builtin_amdgcn_mfma_f32_16x16x32_bf16(a, b0, acc0, 0, 0, 0);
            acc1 = __builtin_amdgcn_mfma_f32_16x16x32_bf16(a, b1, acc1, 0, 0, 0);
            acc2 = __builtin_amdgcn_mfma_f32_16x16x32_bf16(a, b2, acc2, 0, 0, 0);
            acc3 = __builtin_amdgcn_mfma_f32_16x16x32_bf16(a, b3, acc3, 0, 0, 0);
        }
    }

#define STORE_T(ACC, ft)                                                      \
    {                                                                         \
        int f = (ft) * 16 + mrow;                                             \
        size_t o = (size_t)(base + kg * 4) * DD + f;                          \
        out[o         ] = ACC[0] + c0v[ft] + ind0 * c1v[ft];                  \
        out[o + DD    ] = ACC[1] + c0v[ft] + ind1 * c1v[ft];                  \
        out[o + 2 * DD] = ACC[2] + c0v[ft] + ind2 * c1v[ft];                  \
        out[o + 3 * DD] = ACC[3] + c0v[ft] + ind3 * c1v[ft];                  \
    }
    STORE_T(acc0, 0) STORE_T(acc1, 1) STORE_T(acc2, 2) STORE_T(acc3, 3)
#undef STORE_T
}

extern "C" void kernel_launch(void* const* d_in, const int* in_sizes, int n_in,
                              void* d_out, int out_size, void* d_ws, size_t ws_size,
                              hipStream_t stream)
{
    const float* x   = (const float*)d_in[0];
    const int*   ei  = (const int*)d_in[1];
    const float* W1l = (const float*)d_in[2];
    const float* b1l = (const float*)d_in[3];
    const float* W1r = (const float*)d_in[4];
    const float* W2l = (const float*)d_in[5];
    const float* b2l = (const float*)d_in[6];
    const float* W2r = (const float*)d_in[7];
    float* out = (float*)d_out;

    int nN = in_sizes[0] / DD;   // 100000
    int nE = in_sizes[1] / 2;    // 1600000
    const int* src = ei;
    const int* dst = ei + nE;

    int nbuck = (nN + 127) >> BSHIFT;          // 782
    int cchunk = (nE + CBLK - 1) / CBLK;       // 3125
    int schunk = cchunk * 2;                   // 6250

    // ws layout (float-sized slots):
    // rs[nN+1] | partialCnt[nbuck*CBLK] | bucketTot[nbuck] | bucketBase[nbuck+1] |
    // csr[nE] | buckEdges[nE] (aliased later by xq, nN*64 bytes) |
    // MT1,MT2,MT3 | c0,c1 | agg1h[nN*32] | agg2h[nN*32] | agg1q[nN*16] |
    // indf[nN] | Wp[12288 bf16]          (~47 MB)
    int* rs         = (int*)d_ws;
    int* partialCnt = rs + nN + 1;
    int* bucketTot  = partialCnt + (size_t)nbuck * CBLK;
    int* bucketBase = bucketTot + nbuck;
    int* csr        = bucketBase + nbuck + 1;
    int* buckEdges  = csr + nE;
    uchar_t* xq     = (uchar_t*)buckEdges;     // alias: dead after finalize
    size_t ofs = (size_t)(buckEdges + nE - (int*)d_ws);
    ofs = (ofs + 3) & ~(size_t)3;
    float* MT1 = (float*)d_ws + ofs;
    float* MT2 = MT1 + DD * DD;
    float* MT3 = MT2 + DD * DD;
    float* c0 = MT3 + DD * DD;
    float* c1 = c0 + DD;
    float* agg1h_f = c1 + DD;
    float* agg2h_f = agg1h_f + (size_t)nN * 32;
    float* agg1q_f = agg2h_f + (size_t)nN * 32;
    float* indf    = agg1q_f + (size_t)nN * 16;
    ushort_t* Wp   = (ushort_t*)(indf + nN);
    ushort_t* agg1h = (ushort_t*)agg1h_f;
    ushort_t* agg2h = (ushort_t*)agg2h_f;
    uchar_t*  agg1q = (uchar_t*)agg1q_f;

    int ncv  = (nN * 8 + 255) / 256;           // tofp8 blocks (8 elems/thread)
    int nagg = (nN + 31) / 32;                 // aggregate blocks
    int nmf  = (nN / 16 + 3) / 4;              // mfma dense blocks

    // CSR build — bucketed, zero global atomics, all-coalesced streams
    bucket_count<<<CBLK, 256, 0, stream>>>(dst, partialCnt, nE, cchunk, nbuck);
    bucket_scanblocks<<<nbuck, CBLK, 0, stream>>>(partialCnt, bucketTot);
    bucket_scanbase<<<1, 1024, 0, stream>>>(bucketTot, bucketBase, rs, nbuck, nN);
    bucket_scatter<<<SBLK, 256, 0, stream>>>(src, dst, partialCnt, bucketBase,
                                             buckEdges, nE, schunk, nbuck);
    bucket_finalize<<<nbuck, 256, 0, stream>>>(buckEdges, bucketBase, rs, csr,
                                               indf, nN);

    // weight collapse + pack + x -> fp8 (AFTER finalize: xq aliases buckEdges)
    prep_kernel<<<64, 64, 0, stream>>>(W1l, W1r, W2l, W2r, b1l, b2l,
                                       MT1, MT2, MT3, c0, c1);
    pack_weights<<<48, 256, 0, stream>>>(MT1, MT2, MT3, Wp);
    tofp8_kernel<<<ncv, 256, 0, stream>>>(x, xq, nN * 8);

    // two fp8-gather aggregations (1 cache line per row)
    aggregate_fp8<<<nagg, 256, 0, stream>>>(xq, csr, rs, agg1h, agg1q, nN);
    aggregate_fp8<<<nagg, 256, 0, stream>>>(agg1q, csr, rs, agg2h,
                                            (uchar_t*)nullptr, nN);

    // MFMA dense: agg2/agg1 bf16 + x f32 (converted in-reg)
    tri_dense_mfma<<<nmf, 256, 0, stream>>>(agg2h, agg1h, x, Wp,
                                            c0, c1, indf, out, nN);
}

// Round 22
// 131.229 us; speedup vs baseline: 1.0799x; 1.0229x over previous
//
#include <hip/hip_runtime.h>

#define DD 64
#define BSHIFT 7                 // 128 nodes per bucket
#define NBUCK_MAX 800
#define SEGCAP 4096
#define CBLK 512                 // count blocks (chunks)
#define SBLK 256                 // scatter blocks (= CBLK/2, pairs of chunks)

typedef unsigned short ushort_t;
typedef unsigned char uchar_t;
typedef __attribute__((ext_vector_type(8))) short bf16x8;
typedef __attribute__((ext_vector_type(4))) short bf16x4;
typedef __attribute__((ext_vector_type(4))) float f32x4;
typedef __attribute__((ext_vector_type(2))) float f32x2;

#if defined(__has_builtin)
#if __has_builtin(__builtin_amdgcn_cvt_pk_f32_fp8) && __has_builtin(__builtin_amdgcn_cvt_pk_fp8_f32)
#define HW_FP8 1
#endif
#endif
#ifndef HW_FP8
#define HW_FP8 0
#endif

static __device__ __forceinline__ unsigned short f2bf(float f)
{
    unsigned u = __float_as_uint(f);
    unsigned r = (u + 0x7FFFu + ((u >> 16) & 1u)) >> 16;   // round-nearest-even
    return (unsigned short)r;
}

// ---- OCP e4m3fn helpers (HW cvt on gfx950; exact SW fallback via 2^±120) --
static __device__ __forceinline__ unsigned f2q8_sw(float f)
{
    unsigned u = __float_as_uint(f);
    unsigned s = (u >> 31) << 7;
    unsigned um = __float_as_uint(__uint_as_float(u & 0x7FFFFFFFu) * 0x1.0p-120f);
    unsigned q = (um + 0x7FFFFu + ((um >> 20) & 1u)) >> 20;
    if (q > 0x7Eu) q = 0x7Eu;
    return s | q;
}
static __device__ __forceinline__ float q2f_sw(unsigned b)
{
    unsigned u = ((b & 0x80u) << 24) | ((b & 0x7Fu) << 20);
    return __uint_as_float(u) * 0x1.0p120f;
}
template<int WORD>
static __device__ __forceinline__ f32x2 cvt2(unsigned u)
{
#if HW_FP8
    return __builtin_amdgcn_cvt_pk_f32_fp8(u, WORD);
#else
    unsigned b0 = (u >> (WORD * 16)) & 0xFFu;
    unsigned b1 = (u >> (WORD * 16 + 8)) & 0xFFu;
    f32x2 r; r[0] = q2f_sw(b0); r[1] = q2f_sw(b1);
    return r;
#endif
}
template<int WORD>
static __device__ __forceinline__ unsigned pk8(float x, float y, unsigned old)
{
#if HW_FP8
    return __builtin_amdgcn_cvt_pk_fp8_f32(x, y, old, WORD);
#else
    unsigned q = f2q8_sw(x) | (f2q8_sw(y) << 8);
    return WORD ? ((old & 0x0000FFFFu) | (q << 16)) : ((old & 0xFFFF0000u) | q);
#endif
}

// ================= bucketed CSR build (no global atomics) =================

__global__ __launch_bounds__(256)
void bucket_count(const int* __restrict__ dst, int* __restrict__ partialCnt,
                  int nE, int chunk, int nbuck)
{
    __shared__ int bins[NBUCK_MAX];
    int blk = blockIdx.x, t = threadIdx.x;
    for (int i = t; i < nbuck; i += 256) bins[i] = 0;
    __syncthreads();
    int e0 = blk * chunk;
    int e1 = e0 + chunk; if (e1 > nE) e1 = nE;
    for (int e = e0 + t; e < e1; e += 256)
        atomicAdd(&bins[dst[e] >> BSHIFT], 1);
    __syncthreads();
    for (int i = t; i < nbuck; i += 256)
        partialCnt[(size_t)i * CBLK + blk] = bins[i];
}

__global__ __launch_bounds__(CBLK)
void bucket_scanblocks(int* __restrict__ partialCnt, int* __restrict__ bucketTot)
{
    __shared__ int s[CBLK];
    int b = blockIdx.x, t = threadIdx.x;
    int v = partialCnt[(size_t)b * CBLK + t];
    s[t] = v;
    __syncthreads();
    for (int off = 1; off < CBLK; off <<= 1) {
        int u = (t >= off) ? s[t - off] : 0;
        __syncthreads();
        s[t] += u;
        __syncthreads();
    }
    partialCnt[(size_t)b * CBLK + t] = s[t] - v;   // exclusive
    if (t == CBLK - 1) bucketTot[b] = s[CBLK - 1];
}

__global__ __launch_bounds__(1024)
void bucket_scanbase(const int* __restrict__ bucketTot, int* __restrict__ bucketBase,
                     int* __restrict__ rs, int nbuck, int nN)
{
    __shared__ int s[1024];
    int t = threadIdx.x;
    int v = (t < nbuck) ? bucketTot[t] : 0;
    s[t] = v;
    __syncthreads();
    for (int off = 1; off < 1024; off <<= 1) {
        int u = (t >= off) ? s[t - off] : 0;
        __syncthreads();
        s[t] += u;
        __syncthreads();
    }
    if (t < nbuck) bucketBase[t] = s[t] - v;
    if (t == nbuck - 1) {
        bucketBase[nbuck] = s[t];
        rs[nN] = s[t];                // == nE
    }
}

__global__ __launch_bounds__(256)
void bucket_scatter(const int* __restrict__ src, const int* __restrict__ dst,
                    const int* __restrict__ partialCnt,
                    const int* __restrict__ bucketBase,
                    int* __restrict__ buckEdges, int nE, int chunk, int nbuck)
{
    __shared__ int bins[NBUCK_MAX];
    __shared__ int wOff[NBUCK_MAX];
    int blk = blockIdx.x, t = threadIdx.x;
    for (int i = t; i < nbuck; i += 256) {
        bins[i] = 0;
        wOff[i] = bucketBase[i] + partialCnt[(size_t)i * CBLK + 2 * blk];
    }
    __syncthreads();
    int e0 = blk * chunk;
    int e1 = e0 + chunk; if (e1 > nE) e1 = nE;
    for (int e = e0 + t; e < e1; e += 256) {
        int d = dst[e];
        int sv = src[e];
        int bb = d >> BSHIFT;
        int r = atomicAdd(&bins[bb], 1);
        buckEdges[wOff[bb] + r] = sv | ((d & 127) << 17);
    }
}

__global__ __launch_bounds__(256)
void bucket_finalize(const int* __restrict__ buckEdges,
                     const int* __restrict__ bucketBase,
                     int* __restrict__ rs, int* __restrict__ csr,
                     float* __restrict__ indf, int nN)
{
    __shared__ int eLds[SEGCAP];
    __shared__ int segLds[SEGCAP];
    __shared__ int deg[128];
    __shared__ int basec[128];
    __shared__ int cur[128];
    int b = blockIdx.x, t = threadIdx.x;
    int e0 = bucketBase[b], e1 = bucketBase[b + 1];
    int nb = e1 - e0;
    bool staged = (nb <= SEGCAP);
    if (t < 128) deg[t] = 0;
    __syncthreads();
    for (int i = t; i < nb; i += 256) {
        int p = buckEdges[e0 + i];
        if (staged) eLds[i] = p;
        atomicAdd(&deg[(p >> 17) & 127], 1);
    }
    __syncthreads();
    if (t < 128) basec[t] = deg[t];
    __syncthreads();
    for (int off = 1; off < 128; off <<= 1) {
        int u = 0;
        if (t < 128 && t >= off) u = basec[t - off];
        __syncthreads();
        if (t < 128) basec[t] += u;
        __syncthreads();
    }
    int nodeBase = b << BSHIFT;
    if (t < 128) {
        int node = nodeBase + t;
        int ex = basec[t] - deg[t];
        if (node < nN) {
            rs[node] = e0 + ex;
            indf[node] = deg[t] > 0 ? 1.0f : 0.0f;
        }
        cur[t] = ex;
    }
    __syncthreads();
    for (int i = t; i < nb; i += 256) {
        int p = staged ? eLds[i] : buckEdges[e0 + i];
        int dl = (p >> 17) & 127;
        int slot = atomicAdd(&cur[dl], 1);
        int sv = p & 0x1FFFF;
        if (staged) segLds[slot] = sv;
        else        csr[e0 + slot] = sv;
    }
    __syncthreads();
    if (staged)
        for (int i = t; i < nb; i += 256)
            csr[e0 + i] = segLds[i];
}

// ---------- fp32 -> fp8 conversion of x (8 elems/thread) ----------
__global__ __launch_bounds__(256)
void tofp8_kernel(const float* __restrict__ in, uchar_t* __restrict__ outq,
                  int nTot8)
{
    int i = blockIdx.x * 256 + threadIdx.x;
    if (i >= nTot8) return;
    float4 v0 = *(const float4*)(in + (size_t)i * 8);
    float4 v1 = *(const float4*)(in + (size_t)i * 8 + 4);
    unsigned w0 = pk8<0>(v0.x, v0.y, 0u);
    w0 = pk8<1>(v0.z, v0.w, w0);
    unsigned w1 = pk8<0>(v1.x, v1.y, 0u);
    w1 = pk8<1>(v1.z, v1.w, w1);
    uint2 o; o.x = w0; o.y = w1;
    *(uint2*)(outq + (size_t)i * 8) = o;
}

// ---------- weight precompute: collapse the two layers ----------
__global__ void prep_kernel(const float* __restrict__ W1l,
                            const float* __restrict__ W1r,
                            const float* __restrict__ W2l,
                            const float* __restrict__ W2r,
                            const float* __restrict__ b1,
                            const float* __restrict__ b2,
                            float* __restrict__ MT1, float* __restrict__ MT2,
                            float* __restrict__ MT3, float* __restrict__ c0,
                            float* __restrict__ c1)
{
    int f = blockIdx.x;      // 64 blocks
    int k = threadIdx.x;     // 64 threads
    float m1 = 0.f, m2 = 0.f, m3 = 0.f;
    for (int j = 0; j < DD; ++j) {
        float a2l = W2l[f * DD + j];
        float a2r = W2r[f * DD + j];
        float w1l = W1l[j * DD + k];
        float w1r = W1r[j * DD + k];
        m1 = fmaf(a2l, w1l, m1);
        m2 = fmaf(a2l, w1r, m2);
        m2 = fmaf(a2r, w1l, m2);
        m3 = fmaf(a2r, w1r, m3);
    }
    MT1[k * DD + f] = m1;
    MT2[k * DD + f] = m2;
    MT3[k * DD + f] = m3;
    float t1 = W2l[f * DD + k] * b1[k];
    float t0 = W2r[f * DD + k] * b1[k];
    for (int off = 1; off < 64; off <<= 1) {
        t1 += __shfl_xor(t1, off);
        t0 += __shfl_xor(t0, off);
    }
    if (k == 0) {
        c1[f] = t1;
        c0[f] = t0 + b2[f];
    }
}

// ---------- pack weights into MFMA B-fragment order (bf16) ----------
// k = (l>>4)*4 + (e&3) + 16*(e>>2), col = l&15 (verified by R19 passing).
__global__ __launch_bounds__(256)
void pack_weights(const float* __restrict__ MT1, const float* __restrict__ MT2,
                  const float* __restrict__ MT3, ushort_t* __restrict__ Wp)
{
    int idx = blockIdx.x * 256 + threadIdx.x;     // 0..12287
    if (idx >= 12288) return;
    int e    = idx & 7;
    int lane = (idx >> 3) & 63;
    int ft   = (idx >> 9) & 3;
    int kt   = (idx >> 11) & 1;
    int m    = idx >> 12;
    int kin  = ((lane >> 4) * 4) + (e & 3) + 16 * (e >> 2);
    int gk   = kt * 32 + kin;
    int f    = ft * 16 + (lane & 15);
    const float* MT = (m == 0) ? MT1 : (m == 1) ? MT2 : MT3;
    Wp[idx] = f2bf(MT[gk * DD + f]);
}

// ---------- aggregation over fp8 rows, packed-math accumulate ----------
// 8-lane group per node; lane gl owns features [gl*8, gl*8+8) held as
// 4x f32x2 per acc-set -> vector '+='/'fma' emit v_pk_add/fma_f32 (2 ops/inst),
// cutting per-row VALU from 12 to 8 lane-ops. fp32 accum; bf16 (+ opt fp8) out.
__global__ __launch_bounds__(256, 4)
void aggregate_fp8(const uchar_t* __restrict__ xq,
                   const int* __restrict__ csr,
                   const int* __restrict__ rs,
                   ushort_t* __restrict__ aggrh,
                   uchar_t* __restrict__ aggrq,     // may be null
                   int nN)
{
    int lane = threadIdx.x & 63;
    int w = threadIdx.x >> 6;
    int g  = lane >> 3;        // group: node owner
    int gl = lane & 7;         // lane within group
    int node = (blockIdx.x * 4 + w) * 8 + g;
    int valid = node < nN;
    int nd = valid ? node : nN - 1;
    int beg = rs[nd], end = rs[nd + 1];
    int deg = end - beg;

    f32x2 a0p = {0,0}, a0q = {0,0}, a0r = {0,0}, a0s = {0,0};
    f32x2 a1p = {0,0}, a1q = {0,0}, a1r = {0,0}, a1s = {0,0};
    f32x2 a2p = {0,0}, a2q = {0,0}, a2r = {0,0}, a2s = {0,0};
    f32x2 a3p = {0,0}, a3q = {0,0}, a3r = {0,0}, a3s = {0,0};

#define ROWA(S, P, Q, R, T)                                                   \
    {                                                                         \
        uint2 v = *(const uint2*)(xq + (size_t)(S) * DD + gl * 8);            \
        P += cvt2<0>(v.x); Q += cvt2<1>(v.x);                                 \
        R += cvt2<0>(v.y); T += cvt2<1>(v.y);                                 \
    }
#define ROWM(S, MM, P, Q, R, T)                                               \
    {                                                                         \
        uint2 v = *(const uint2*)(xq + (size_t)(S) * DD + gl * 8);            \
        P += MM * cvt2<0>(v.x); Q += MM * cvt2<1>(v.x);                       \
        R += MM * cvt2<0>(v.y); T += MM * cvt2<1>(v.y);                       \
    }

    for (int ch = 0; ch < deg; ch += 8) {
        int ii = ch + gl;
        int myIdx = csr[(ii < deg) ? (beg + ii) : beg];
        int lb = g << 3;
        if (ch + 8 <= deg) {           // full chunk: no masks
            int s0 = __shfl(myIdx, lb + 0);
            int s1 = __shfl(myIdx, lb + 1);
            int s2 = __shfl(myIdx, lb + 2);
            int s3 = __shfl(myIdx, lb + 3);
            ROWA(s0, a0p, a0q, a0r, a0s) ROWA(s1, a1p, a1q, a1r, a1s)
            ROWA(s2, a2p, a2q, a2r, a2s) ROWA(s3, a3p, a3q, a3r, a3s)
            int s4 = __shfl(myIdx, lb + 4);
            int s5 = __shfl(myIdx, lb + 5);
            int s6 = __shfl(myIdx, lb + 6);
            int s7 = __shfl(myIdx, lb + 7);
            ROWA(s4, a0p, a0q, a0r, a0s) ROWA(s5, a1p, a1q, a1r, a1s)
            ROWA(s6, a2p, a2q, a2r, a2s) ROWA(s7, a3p, a3q, a3r, a3s)
        } else {                       // tail chunk: masked
            int rem = deg - ch;
            int s0 = __shfl(myIdx, lb + 0);
            int s1 = __shfl(myIdx, lb + 1);
            int s2 = __shfl(myIdx, lb + 2);
            int s3 = __shfl(myIdx, lb + 3);
            float m0 = (0 < rem) ? 1.f : 0.f;
            float m1 = (1 < rem) ? 1.f : 0.f;
            float m2 = (2 < rem) ? 1.f : 0.f;
            float m3 = (3 < rem) ? 1.f : 0.f;
            ROWM(s0, m0, a0p, a0q, a0r, a0s) ROWM(s1, m1, a1p, a1q, a1r, a1s)
            ROWM(s2, m2, a2p, a2q, a2r, a2s) ROWM(s3, m3, a3p, a3q, a3r, a3s)
            int s4 = __shfl(myIdx, lb + 4);
            int s5 = __shfl(myIdx, lb + 5);
            int s6 = __shfl(myIdx, lb + 6);
            int s7 = __shfl(myIdx, lb + 7);
            float m4 = (4 < rem) ? 1.f : 0.f;
            float m5 = (5 < rem) ? 1.f : 0.f;
            float m6 = (6 < rem) ? 1.f : 0.f;
            float m7 = (7 < rem) ? 1.f : 0.f;
            ROWM(s4, m4, a0p, a0q, a0r, a0s) ROWM(s5, m5, a1p, a1q, a1r, a1s)
            ROWM(s6, m6, a2p, a2q, a2r, a2s) ROWM(s7, m7, a3p, a3q, a3r, a3s)
        }
    }
#undef ROWA
#undef ROWM

    if (valid) {
        float inv = 1.0f / (float)(deg > 0 ? deg : 1);
        f32x2 P = ((a0p + a1p) + (a2p + a3p)) * inv;
        f32x2 Q = ((a0q + a1q) + (a2q + a3q)) * inv;
        f32x2 R = ((a0r + a1r) + (a2r + a3r)) * inv;
        f32x2 T = ((a0s + a1s) + (a2s + a3s)) * inv;
        uint4 o;
        o.x = (unsigned)f2bf(P[0]) | ((unsigned)f2bf(P[1]) << 16);
        o.y = (unsigned)f2bf(Q[0]) | ((unsigned)f2bf(Q[1]) << 16);
        o.z = (unsigned)f2bf(R[0]) | ((unsigned)f2bf(R[1]) << 16);
        o.w = (unsigned)f2bf(T[0]) | ((unsigned)f2bf(T[1]) << 16);
        *(uint4*)(aggrh + (size_t)node * DD + gl * 8) = o;
        if (aggrq) {
            unsigned w0 = pk8<0>(P[0], P[1], 0u);
            w0 = pk8<1>(Q[0], Q[1], w0);
            unsigned w1 = pk8<0>(R[0], R[1], 0u);
            w1 = pk8<1>(T[0], T[1], w1);
            uint2 q; q.x = w0; q.y = w1;
            *(uint2*)(aggrq + (size_t)node * DD + gl * 8) = q;
        }
    }
}

// ---------- MFMA tri-dense: out = agg2@M1.T + agg1@M2.T + x@M3.T + bias ----
__global__ __launch_bounds__(256)
void tri_dense_mfma(const ushort_t* __restrict__ agg2h,
                    const ushort_t* __restrict__ agg1h,
                    const float* __restrict__ xf,
                    const ushort_t* __restrict__ Wp,
                    const float* __restrict__ c0,
                    const float* __restrict__ c1,
                    const float* __restrict__ indf,
                    float* __restrict__ out, int nN)
{
    int lane = threadIdx.x & 63;
    int w = threadIdx.x >> 6;
    int base = (blockIdx.x * 4 + w) * 16;
    if (base >= nN) return;
    int mrow = lane & 15;          // A row within tile / D col (=f low bits)
    int kg   = lane >> 4;          // k-group / D row-group
    size_t rowoff = (size_t)(base + mrow) * DD + kg * 4;

    bf16x4 aLo[2][2], aHi[2][2];
#pragma unroll
    for (int m = 0; m < 2; ++m) {
        const ushort_t* sp = (m == 0) ? agg2h : agg1h;
#pragma unroll
        for (int kt = 0; kt < 2; ++kt) {
            aLo[m][kt] = *(const bf16x4*)(sp + rowoff + kt * 32);
            aHi[m][kt] = *(const bf16x4*)(sp + rowoff + kt * 32 + 16);
        }
    }
    float4 xlo[2], xhi[2];
#pragma unroll
    for (int kt = 0; kt < 2; ++kt) {
        xlo[kt] = *(const float4*)(xf + rowoff + kt * 32);
        xhi[kt] = *(const float4*)(xf + rowoff + kt * 32 + 16);
    }
    float ind0 = indf[base + kg * 4 + 0];
    float ind1 = indf[base + kg * 4 + 1];
    float ind2 = indf[base + kg * 4 + 2];
    float ind3 = indf[base + kg * 4 + 3];
    float c0v[4], c1v[4];
#pragma unroll
    for (int ft = 0; ft < 4; ++ft) {
        c0v[ft] = c0[ft * 16 + mrow];
        c1v[ft] = c1[ft * 16 + mrow];
    }

    f32x4 acc0 = {0,0,0,0}, acc1 = {0,0,0,0}, acc2 = {0,0,0,0}, acc3 = {0,0,0,0};
#pragma unroll
    for (int m = 0; m < 3; ++m) {
#pragma unroll
        for (int kt = 0; kt < 2; ++kt) {
            bf16x8 a;
            if (m < 2) {
                a[0] = aLo[m][kt][0]; a[1] = aLo[m][kt][1];
                a[2] = aLo[m][kt][2]; a[3] = aLo[m][kt][3];
                a[4] = aHi[m][kt][0]; a[5] = aHi[m][kt][1];
                a[6] = aHi[m][kt][2]; a[7] = aHi[m][kt][3];
            } else {
                a[0] = (short)f2bf(xlo[kt].x); a[1] = (short)f2bf(xlo[kt].y);
                a[2] = (short)f2bf(xlo[kt].z); a[3] = (short)f2bf(xlo[kt].w);
                a[4] = (short)f2bf(xhi[kt].x); a[5] = (short)f2bf(xhi[kt].y);
                a[6] = (short)f2bf(xhi[kt].z); a[7] = (short)f2bf(xhi[kt].w);
            }
            const ushort_t* wp = Wp + ((m * 2 + kt) * 4) * 512 + lane * 8;
            bf16x8 b0 = *(const bf16x8*)(wp);
            bf16x8 b1 = *(const bf16x8*)(wp + 512);
            bf16x8 b2 = *(const bf16x8*)(wp + 1024);
            bf16x8 b3 = *(const bf16x8*)(wp + 1536);
            acc0 = __builtin_amdgcn_mfma_f32_16x16x32_bf16(a, b0, acc0, 0, 0, 0);
            acc1 = __builtin_amdgcn_mfma_f32_16x16x32_bf16(a, b1, acc1, 0, 0, 0);
            acc2 = __builtin_amdgcn_mfma_f32_16x16x32_bf16(a, b2, acc2, 0, 0, 0);
            acc3 = __builtin_amdgcn_mfma_f32_16x16x32_bf16(a, b3, acc3, 0, 0, 0);
        }
    }

#define STORE_T(ACC, ft)                                                      \
    {                                                                         \
        int f = (ft) * 16 + mrow;                                             \
        size_t o = (size_t)(base + kg * 4) * DD + f;                          \
        out[o         ] = ACC[0] + c0v[ft] + ind0 * c1v[ft];                  \
        out[o + DD    ] = ACC[1] + c0v[ft] + ind1 * c1v[ft];                  \
        out[o + 2 * DD] = ACC[2] + c0v[ft] + ind2 * c1v[ft];                  \
        out[o + 3 * DD] = ACC[3] + c0v[ft] + ind3 * c1v[ft];                  \
    }
    STORE_T(acc0, 0) STORE_T(acc1, 1) STORE_T(acc2, 2) STORE_T(acc3, 3)
#undef STORE_T
}

extern "C" void kernel_launch(void* const* d_in, const int* in_sizes, int n_in,
                              void* d_out, int out_size, void* d_ws, size_t ws_size,
                              hipStream_t stream)
{
    const float* x   = (const float*)d_in[0];
    const int*   ei  = (const int*)d_in[1];
    const float* W1l = (const float*)d_in[2];
    const float* b1l = (const float*)d_in[3];
    const float* W1r = (const float*)d_in[4];
    const float* W2l = (const float*)d_in[5];
    const float* b2l = (const float*)d_in[6];
    const float* W2r = (const float*)d_in[7];
    float* out = (float*)d_out;

    int nN = in_sizes[0] / DD;   // 100000
    int nE = in_sizes[1] / 2;    // 1600000
    const int* src = ei;
    const int* dst = ei + nE;

    int nbuck = (nN + 127) >> BSHIFT;          // 782
    int cchunk = (nE + CBLK - 1) / CBLK;       // 3125
    int schunk = cchunk * 2;                   // 6250

    int* rs         = (int*)d_ws;
    int* partialCnt = rs + nN + 1;
    int* bucketTot  = partialCnt + (size_t)nbuck * CBLK;
    int* bucketBase = bucketTot + nbuck;
    int* csr        = bucketBase + nbuck + 1;
    int* buckEdges  = csr + nE;
    uchar_t* xq     = (uchar_t*)buckEdges;     // alias: dead after finalize
    size_t ofs = (size_t)(buckEdges + nE - (int*)d_ws);
    ofs = (ofs + 3) & ~(size_t)3;
    float* MT1 = (float*)d_ws + ofs;
    float* MT2 = MT1 + DD * DD;
    float* MT3 = MT2 + DD * DD;
    float* c0 = MT3 + DD * DD;
    float* c1 = c0 + DD;
    float* agg1h_f = c1 + DD;
    float* agg2h_f = agg1h_f + (size_t)nN * 32;
    float* agg1q_f = agg2h_f + (size_t)nN * 32;
    float* indf    = agg1q_f + (size_t)nN * 16;
    ushort_t* Wp   = (ushort_t*)(indf + nN);
    ushort_t* agg1h = (ushort_t*)agg1h_f;
    ushort_t* agg2h = (ushort_t*)agg2h_f;
    uchar_t*  agg1q = (uchar_t*)agg1q_f;

    int ncv  = (nN * 8 + 255) / 256;           // tofp8 blocks
    int nagg = (nN + 31) / 32;                 // aggregate blocks
    int nmf  = (nN / 16 + 3) / 4;              // mfma dense blocks

    // CSR build — bucketed, zero global atomics, all-coalesced streams
    bucket_count<<<CBLK, 256, 0, stream>>>(dst, partialCnt, nE, cchunk, nbuck);
    bucket_scanblocks<<<nbuck, CBLK, 0, stream>>>(partialCnt, bucketTot);
    bucket_scanbase<<<1, 1024, 0, stream>>>(bucketTot, bucketBase, rs, nbuck, nN);
    bucket_scatter<<<SBLK, 256, 0, stream>>>(src, dst, partialCnt, bucketBase,
                                             buckEdges, nE, schunk, nbuck);
    bucket_finalize<<<nbuck, 256, 0, stream>>>(buckEdges, bucketBase, rs, csr,
                                               indf, nN);

    // weight collapse + pack + x -> fp8 (AFTER finalize: xq aliases buckEdges)
    prep_kernel<<<64, 64, 0, stream>>>(W1l, W1r, W2l, W2r, b1l, b2l,
                                       MT1, MT2, MT3, c0, c1);
    pack_weights<<<48, 256, 0, stream>>>(MT1, MT2, MT3, Wp);
    tofp8_kernel<<<ncv, 256, 0, stream>>>(x, xq, nN * 8);

    // two fp8-gather aggregations (1 cache line per row, packed-math accum)
    aggregate_fp8<<<nagg, 256, 0, stream>>>(xq, csr, rs, agg1h, agg1q, nN);
    aggregate_fp8<<<nagg, 256, 0, stream>>>(agg1q, csr, rs, agg2h,
                                            (uchar_t*)nullptr, nN);

    // MFMA dense: agg2/agg1 bf16 + x f32 (converted in-reg)
    tri_dense_mfma<<<nmf, 256, 0, stream>>>(agg2h, agg1h, x, Wp,
                                            c0, c1, indf, out, nN);
}